// Round 1
// baseline (374.271 us; speedup 1.0000x reference)
//
#include <hip/hip_runtime.h>

typedef unsigned short u16;
typedef __bf16 bf16x8 __attribute__((ext_vector_type(8)));
typedef float f32x4 __attribute__((ext_vector_type(4)));

__device__ __forceinline__ u16 f2bf(float f) {
  union { float f; unsigned int u; } v; v.f = f;
  unsigned int u = v.u;
  u += 0x7fffu + ((u >> 16) & 1u);
  return (u16)(u >> 16);
}
__device__ __forceinline__ float bf2f(u16 h) {
  union { unsigned int u; float f; } v; v.u = ((unsigned int)h) << 16; return v.f;
}

// ---------------- cast weights fp32 -> bf16 ----------------
__global__ __launch_bounds__(256) void cast_weights(
    const float* __restrict__ w0, const float* __restrict__ w1,
    const float* __restrict__ w2, const float* __restrict__ w3,
    u16* __restrict__ o0, u16* __restrict__ o1,
    u16* __restrict__ o2, u16* __restrict__ o3) {
  int i = blockIdx.x * 256 + threadIdx.x;
  if (i < 110592) o0[i] = f2bf(w0[i]);   // qkv_w 576x192
  if (i < 36864)  o1[i] = f2bf(w1[i]);   // proj_w 192x192
  if (i < 221184) o2[i] = f2bf(w2[i]);   // fc1_w 1152x192
  if (i < 221184) o3[i] = f2bf(w3[i]);   // fc2_w 192x1152
}

// ---------------- layernorm (fp32 in, bf16 out), 1 wave per row of 192 ----------------
__global__ __launch_bounds__(256) void ln_kernel(
    const float* __restrict__ x, const float* __restrict__ g,
    const float* __restrict__ b, u16* __restrict__ out) {
  int row = blockIdx.x * 4 + (threadIdx.x >> 6);
  int lane = threadIdx.x & 63;
  const float* xr = x + (long)row * 192;
  float e0 = xr[lane], e1 = xr[lane + 64], e2 = xr[lane + 128];
  float s = e0 + e1 + e2;
  #pragma unroll
  for (int o = 1; o < 64; o <<= 1) s += __shfl_xor(s, o);
  float mean = s * (1.0f / 192.0f);
  float d0 = e0 - mean, d1 = e1 - mean, d2 = e2 - mean;
  float q = d0 * d0 + d1 * d1 + d2 * d2;
  #pragma unroll
  for (int o = 1; o < 64; o <<= 1) q += __shfl_xor(q, o);
  float rstd = rsqrtf(q * (1.0f / 192.0f) + 1e-5f);
  u16* orow = out + (long)row * 192;
  orow[lane]       = f2bf(d0 * rstd * g[lane]       + b[lane]);
  orow[lane + 64]  = f2bf(d1 * rstd * g[lane + 64]  + b[lane + 64]);
  orow[lane + 128] = f2bf(d2 * rstd * g[lane + 128] + b[lane + 128]);
}

// ---------------- MFMA GEMM: out[M,N] = A[M,K] @ W[N,K]^T + bias ----------------
// MODE 0: store bf16. MODE 1: GELU(exact) then store bf16. MODE 2: +resid(fp32), store fp32.
// Block tile 128x64, 4 waves in 2x2, each wave 64x32 (4x2 MFMA tiles of 16x16x32 bf16).
template<int MODE>
__global__ __launch_bounds__(256) void gemm_kernel(
    const u16* __restrict__ A, const u16* __restrict__ W,
    const float* __restrict__ bias, const float* __restrict__ resid,
    void* __restrict__ out, int N, int K) {
  __shared__ u16 lA[128 * 40];   // stride 40 (=80B) to spread banks
  __shared__ u16 lB[64 * 40];
  int tid = threadIdx.x;
  int wave = tid >> 6, lane = tid & 63;
  int wm = wave >> 1, wn = wave & 1;
  int quad = lane >> 4, l15 = lane & 15;
  long bm = (long)blockIdx.x * 128;
  int bn = blockIdx.y * 64;
  int r = tid >> 2, cg = (tid & 3) * 8;
  f32x4 acc[4][2] = {};
  for (int k0 = 0; k0 < K; k0 += 32) {
    uint4 a0 = *(const uint4*)(A + (bm + r) * K + k0 + cg);
    uint4 a1 = *(const uint4*)(A + (bm + 64 + r) * K + k0 + cg);
    uint4 b0 = *(const uint4*)(W + (long)(bn + r) * K + k0 + cg);
    __syncthreads();
    *(uint4*)&lA[r * 40 + cg] = a0;
    *(uint4*)&lA[(64 + r) * 40 + cg] = a1;
    *(uint4*)&lB[r * 40 + cg] = b0;
    __syncthreads();
    bf16x8 af[4], bfr[2];
    #pragma unroll
    for (int mt = 0; mt < 4; mt++)
      af[mt] = *(const bf16x8*)&lA[(wm * 64 + mt * 16 + l15) * 40 + quad * 8];
    #pragma unroll
    for (int nt = 0; nt < 2; nt++)
      bfr[nt] = *(const bf16x8*)&lB[(wn * 32 + nt * 16 + l15) * 40 + quad * 8];
    #pragma unroll
    for (int mt = 0; mt < 4; mt++)
      #pragma unroll
      for (int nt = 0; nt < 2; nt++)
        acc[mt][nt] = __builtin_amdgcn_mfma_f32_16x16x32_bf16(af[mt], bfr[nt], acc[mt][nt], 0, 0, 0);
  }
  #pragma unroll
  for (int mt = 0; mt < 4; mt++) {
    #pragma unroll
    for (int nt = 0; nt < 2; nt++) {
      int col = bn + wn * 32 + nt * 16 + l15;
      float bi = bias[col];
      #pragma unroll
      for (int j = 0; j < 4; j++) {
        long row = bm + wm * 64 + mt * 16 + quad * 4 + j;
        float v = acc[mt][nt][j] + bi;
        long idx = row * N + col;
        if (MODE == 0) {
          ((u16*)out)[idx] = f2bf(v);
        } else if (MODE == 1) {
          v = 0.5f * v * (1.0f + erff(v * 0.70710678118f));
          ((u16*)out)[idx] = f2bf(v);
        } else {
          ((float*)out)[idx] = resid[idx] + v;
        }
      }
    }
  }
}

// ---------------- windowed attention, one block per (window, head) ----------------
// qkv: [50176, 576] bf16 rows in ORIGINAL (B,H,W) layout; shift handled via rowmap.
// Writes attn out [50176, 192] bf16 back through the same rowmap (inverse shift).
__global__ __launch_bounds__(256) void attn_kernel(
    const u16* __restrict__ qkv, const float* __restrict__ rpb,
    u16* __restrict__ attn) {
  __shared__ float ql[49 * 36], kl[49 * 36], vl[49 * 36];
  __shared__ float S[49 * 52];
  __shared__ int rowmap[49];
  int tid = threadIdx.x;
  int win = blockIdx.x, head = blockIdx.y;
  int b = win >> 6, wy = (win >> 3) & 7, wx = win & 7;
  if (tid < 49) {
    int i = tid / 7, j = tid - i * 7;
    int y  = (wy * 7 + i + 3) % 56;   // roll(-SHIFT): shifted[y] = src[(y+3)%56]
    int xx = (wx * 7 + j + 3) % 56;
    rowmap[tid] = b * 3136 + y * 56 + xx;
  }
  __syncthreads();
  const float scale = 0.17677669529663687f;  // 32^-0.5
  for (int t = tid; t < 49 * 32; t += 256) {
    int n = t >> 5, d = t & 31;
    long base = (long)rowmap[n] * 576 + head * 32 + d;
    ql[n * 36 + d] = bf2f(qkv[base]) * scale;
    kl[n * 36 + d] = bf2f(qkv[base + 192]);
    vl[n * 36 + d] = bf2f(qkv[base + 384]);
  }
  __syncthreads();
  for (int e = tid; e < 49 * 49; e += 256) {
    int n = e / 49, m = e - n * 49;
    const float4* qp = (const float4*)&ql[n * 36];
    const float4* kp = (const float4*)&kl[m * 36];
    float s = 0.0f;
    #pragma unroll
    for (int d4 = 0; d4 < 8; d4++) {
      float4 a = qp[d4], bb = kp[d4];
      s += a.x * bb.x + a.y * bb.y + a.z * bb.z + a.w * bb.w;
    }
    int ni = n / 7, nj = n - ni * 7, mi = m / 7, mj = m - mi * 7;
    s += rpb[((ni - mi + 6) * 13 + (nj - mj + 6)) * 6 + head];
    S[n * 52 + m] = s;
  }
  __syncthreads();
  if (tid < 49) {
    float mx = -1e30f;
    for (int m = 0; m < 49; m++) mx = fmaxf(mx, S[tid * 52 + m]);
    float sum = 0.0f;
    for (int m = 0; m < 49; m++) {
      float e = __expf(S[tid * 52 + m] - mx);
      S[tid * 52 + m] = e; sum += e;
    }
    float inv = 1.0f / sum;
    for (int m = 0; m < 49; m++) S[tid * 52 + m] *= inv;
  }
  __syncthreads();
  for (int e = tid; e < 49 * 8; e += 256) {
    int n = e >> 3, d4 = (e & 7) * 4;
    float4 o = make_float4(0.f, 0.f, 0.f, 0.f);
    for (int m = 0; m < 49; m++) {
      float p = S[n * 52 + m];
      const float4 vv = *(const float4*)&vl[m * 36 + d4];
      o.x += p * vv.x; o.y += p * vv.y; o.z += p * vv.z; o.w += p * vv.w;
    }
    long gb = (long)rowmap[n] * 192 + head * 32 + d4;
    unsigned int p0 = (unsigned int)f2bf(o.x) | ((unsigned int)f2bf(o.y) << 16);
    unsigned int p1 = (unsigned int)f2bf(o.z) | ((unsigned int)f2bf(o.w) << 16);
    *(uint2*)&attn[gb] = make_uint2(p0, p1);
  }
}

extern "C" void kernel_launch(void* const* d_in, const int* in_sizes, int n_in,
                              void* d_out, int out_size, void* d_ws, size_t ws_size,
                              hipStream_t stream) {
  (void)in_sizes; (void)n_in; (void)out_size; (void)ws_size;
  const float* x      = (const float*)d_in[0];
  // d_in[1], d_in[2] = H, W (ints) — fixed at 56, ignored.
  const float* ln1_g  = (const float*)d_in[3];
  const float* ln1_b  = (const float*)d_in[4];
  const float* qkv_w  = (const float*)d_in[5];
  const float* qkv_b  = (const float*)d_in[6];
  const float* rpb    = (const float*)d_in[7];
  const float* proj_w = (const float*)d_in[8];
  const float* proj_b = (const float*)d_in[9];
  const float* ln2_g  = (const float*)d_in[10];
  const float* ln2_b  = (const float*)d_in[11];
  const float* fc1_w  = (const float*)d_in[12];
  const float* fc1_b  = (const float*)d_in[13];
  const float* fc2_w  = (const float*)d_in[14];
  const float* fc2_b  = (const float*)d_in[15];

  // workspace layout (bytes), M=50176:
  //   [0,            38,535,168)  x2 fp32
  //   [38,535,168,   57,802,752)  hA bf16 (ln1 out; reused as h2 after proj)
  //   [57,802,752,  115,605,504)  qkv bf16  --+ both dead after proj; hid bf16
  //   [115,605,504, 134,873,088)  attn bf16 --+ overlays [57,802,752, 173,408,256)
  //   [173,408,256, 174,587,904)  bf16 weights
  char* ws = (char*)d_ws;
  float* x2   = (float*)(ws + 0);
  u16* hA     = (u16*)(ws + 38535168);
  u16* qkv    = (u16*)(ws + 57802752);
  u16* attn   = (u16*)(ws + 115605504);
  u16* hid    = (u16*)(ws + 57802752);
  u16* wbuf   = (u16*)(ws + 173408256);
  u16* qkv_wb = wbuf;
  u16* proj_wb = wbuf + 110592;
  u16* fc1_wb = wbuf + 147456;
  u16* fc2_wb = wbuf + 368640;

  cast_weights<<<dim3(864), 256, 0, stream>>>(qkv_w, proj_w, fc1_w, fc2_w,
                                              qkv_wb, proj_wb, fc1_wb, fc2_wb);
  ln_kernel<<<dim3(12544), 256, 0, stream>>>(x, ln1_g, ln1_b, hA);
  gemm_kernel<0><<<dim3(392, 9), 256, 0, stream>>>(hA, qkv_wb, qkv_b, nullptr,
                                                   qkv, 576, 192);
  attn_kernel<<<dim3(1024, 6), 256, 0, stream>>>(qkv, rpb, attn);
  gemm_kernel<2><<<dim3(392, 3), 256, 0, stream>>>(attn, proj_wb, proj_b, x,
                                                   x2, 192, 192);
  ln_kernel<<<dim3(12544), 256, 0, stream>>>(x2, ln2_g, ln2_b, hA);
  gemm_kernel<1><<<dim3(392, 18), 256, 0, stream>>>(hA, fc1_wb, fc1_b, nullptr,
                                                    hid, 1152, 192);
  gemm_kernel<2><<<dim3(392, 3), 256, 0, stream>>>(hid, fc2_wb, fc2_b, x2,
                                                   (float*)d_out, 192, 1152);
}